// Round 6
// baseline (36.792 us; speedup 1.0000x reference)
//
#include <hip/hip_runtime.h>
#include <hip/hip_bf16.h>
#include <math.h>

typedef __attribute__((ext_vector_type(8))) short bf16x8;
typedef __attribute__((ext_vector_type(4))) float f32x4;

constexpr int BD = 1024;
constexpr float EPS = 1e-3f;
// d_ws layout
constexpr int WB_MAIN = 32 * 5 * 64 * 8 * 2;    // 163840  [32 ksteps][5 tiles][64 lanes][8 bf16]
constexpr int WB2_OFF = WB_MAIN;                 // w2 frags: 6*64*8*2 = 6144
constexpr int WB3_OFF = WB2_OFF + 6144;          // w3 frags: 4*64*8*2 = 4096
constexpr int CST_OFF = WB3_OFF + 4096;          // 3 floats

// main-kernel LDS geometry (per wave: 2 chunk-buffers of 16 rows x 528B)
constexpr int ROWB = 528;                        // 512B row + 16B pad (= 4 dwords mod 32 banks)
constexpr int BUFB = 16 * ROWB;                  // 8448
constexpr int WAVEB = 2 * BUFB;                  // 16896
// epilogue regions (post-barrier reuse): H1/H2/LC in wave0 area, RED in wave1 area
constexpr int H1 = 0, H2 = 4352, LC = 8704, RED = WAVEB;

__device__ __forceinline__ float wave_allsum(float v) {
#pragma unroll
    for (int m = 1; m < 64; m <<= 1) v += __shfl_xor(v, m, 64);
    return v;
}
__device__ __forceinline__ unsigned short f2bf(float f) {
    __hip_bfloat16 h = __float2bfloat16(f);   // RNE
    unsigned short u; __builtin_memcpy(&u, &h, 2);
    return u;
}
__device__ __forceinline__ float bf2f(unsigned short u) {
    return __uint_as_float(((unsigned)u) << 16);
}
__device__ __forceinline__ float tanh_fast(float x) {
    const float xc = fminf(fmaxf(x, -15.f), 15.f);
    const float e = __expf(2.f * xc);
    return (e - 1.f) * __builtin_amdgcn_rcpf(e + 1.f);
}
__device__ __forceinline__ float sigmoid_fast(float z) {
    return __builtin_amdgcn_rcpf(1.f + __expf(-z));
}

// ---------------- prep: bf16 B-fragments (w1+cross, w2, w3) + cross constants ----------------
__global__ void dcn_prep(const float* __restrict__ w1,
                         const float* __restrict__ cross_w,
                         const float* __restrict__ cross_b,
                         const float* __restrict__ w_out,
                         const float* __restrict__ w2,
                         const float* __restrict__ w3,
                         unsigned short* __restrict__ ws) {
    const int bx = blockIdx.x;
    if (bx == 40) {                       // cross constants
        if (threadIdx.x < 64) {
            const int l = threadIdx.x;
            float q2 = 0.f, q3 = 0.f, Cc = 0.f;
            for (int j = 0; j < 16; ++j) {
                const int k = l * 16 + j;
                const float c0 = cross_b[k], c1 = cross_b[BD + k], c2 = cross_b[2 * BD + k];
                q2 += c0 * cross_w[BD + k];
                q3 += (c0 + c1) * cross_w[2 * BD + k];
                Cc += (c0 + c1 + c2) * w_out[k];
            }
            q2 = wave_allsum(q2); q3 = wave_allsum(q3); Cc = wave_allsum(Cc);
            float* consts = (float*)((char*)ws + CST_OFF);
            if (l == 0) { consts[0] = q2; consts[1] = q3; consts[2] = Cc; }
        }
        return;
    }
    if (bx < 40) {                        // main-GEMM fragments
        const int idx = bx * 256 + threadIdx.x;   // [0, 10240)
        const int g = idx / 320;          // k-step 0..31
        const int rem = idx - g * 320;
        const int t = rem >> 6;           // tile 0..4
        const int l = rem & 63;
        const int c = l & 15;
        const int k0 = g * 32 + (l >> 4) * 8;
        unsigned short o[8] __attribute__((aligned(16)));
#pragma unroll
        for (int j = 0; j < 8; ++j) {
            const int k = k0 + j;
            unsigned short r;
            if (t < 4) {
                r = f2bf(w1[k * 64 + t * 16 + c]);
            } else if (c < 8) {
                const int vsel = c & 3;
                const float v = (vsel < 3) ? cross_w[vsel * BD + k] : w_out[k];
                const unsigned short h = f2bf(v);
                r = (c < 4) ? h : f2bf(v - bf2f(h));
            } else {
                r = 0;
            }
            o[j] = r;
        }
        *(uint4*)(ws + (size_t)idx * 8) = *(const uint4*)o;
        return;
    }
    // bx in 41..43 : tower fragments
    const int slot = (bx - 41) * 256 + threadIdx.x;   // [0, 768)
    if (slot < 384) {                     // w2: f = K*3+T, frag [64][8]
        const int f = slot >> 6, l = slot & 63;
        const int K = f / 3, T = f % 3;
        const int kb = K * 32 + (l >> 4) * 8;
        const int col = T * 16 + (l & 15);
        unsigned short o[8] __attribute__((aligned(16)));
#pragma unroll
        for (int j = 0; j < 8; ++j) o[j] = f2bf(w2[(kb + j) * 48 + col]);
        unsigned short* wb2 = (unsigned short*)((char*)ws + WB2_OFF);
        *(uint4*)(wb2 + (size_t)slot * 8) = *(const uint4*)o;
    } else if (slot < 640) {              // w3: f = K*2+T (zero-padded k>=48, col>=24)
        const int s2 = slot - 384;
        const int f = s2 >> 6, l = s2 & 63;
        const int K = f >> 1, T = f & 1;
        const int kb = K * 32 + (l >> 4) * 8;
        const int col = T * 16 + (l & 15);
        unsigned short o[8] __attribute__((aligned(16)));
#pragma unroll
        for (int j = 0; j < 8; ++j) {
            const int k = kb + j;
            o[j] = (k < 48 && col < 24) ? f2bf(w3[k * 24 + col]) : (unsigned short)0;
        }
        unsigned short* wb3 = (unsigned short*)((char*)ws + WB3_OFF);
        *(uint4*)(wb3 + (size_t)s2 * 8) = *(const uint4*)o;
    }
}

// ---------------- main: 2 waves split K; linear x-loads -> per-wave LDS reshuffle ----------------
__global__ __launch_bounds__(128, 2) void dcn_main(
    const float* __restrict__ x,
    const unsigned short* __restrict__ wbm,
    const unsigned short* __restrict__ w2f,
    const unsigned short* __restrict__ w3f,
    const float* __restrict__ consts,
    const float* __restrict__ b1, const float* __restrict__ g1,
    const float* __restrict__ be1, const float* __restrict__ m1, const float* __restrict__ v1,
    const float* __restrict__ b2, const float* __restrict__ g2,
    const float* __restrict__ be2, const float* __restrict__ m2, const float* __restrict__ v2,
    const float* __restrict__ b3, const float* __restrict__ g3,
    const float* __restrict__ be3, const float* __restrict__ m3, const float* __restrict__ v3,
    const float* __restrict__ w_out, const float* __restrict__ b_out,
    float* __restrict__ out)
{
    __shared__ char sb[2 * WAVEB] __attribute__((aligned(16)));   // 33792 B

    const int tid = threadIdx.x;
    const int l = tid & 63;               // lane
    const int w = tid >> 6;               // wave 0/1 = K half
    const int ar = l & 15;                // fragment row
    const int ag = l >> 4;                // k sub-block
    const int gr0 = blockIdx.x * 16;
    const int woff = w * WAVEB;

    // ---- staging addresses: linear loads, 2 rows x 512B per instruction ----
    const int srow = l >> 5;              // 0/1: which of the row pair
    const int scol = (l & 31) * 4;        // float offset within 128-float chunk
    const float* xw = x + (size_t)(gr0 + srow) * BD + w * 512 + scol;
    char* cdst = &sb[woff + srow * ROWB + scol * 4];

    float4 S[8];
    auto stage = [&](int c) {             // chunk c -> regs (8 x 1KB contiguous loads)
#pragma unroll
        for (int i = 0; i < 8; ++i)
            S[i] = *(const float4*)(xw + (size_t)(i * 2) * BD + c * 128);
    };
    auto commit = [&](int c) {            // regs -> LDS buf (c&1)
        char* d = cdst + (c & 1) * BUFB;
#pragma unroll
        for (int i = 0; i < 8; ++i)
            *(float4*)(d + i * 2 * ROWB) = S[i];
    };

    // ---- B fragments for this wave's k-steps g = w*16 + g_lin ----
    const bf16x8* bb = (const bf16x8*)wbm + (size_t)(w * 16 * 5) * 64 + l;
    bf16x8 Bf[4][5];

    f32x4 acc0 = {0.f,0.f,0.f,0.f}, acc1 = acc0, acc2 = acc0, acc3 = acc0, acc4 = acc0;

    const int abase = woff + ar * ROWB + ag * 32;
    auto kstep = [&](int g_lin, int cbuf) {
        const int s = g_lin & 3;          // step within chunk
        const float4 a0 = *(const float4*)&sb[abase + cbuf + s * 128];
        const float4 a1 = *(const float4*)&sb[abase + cbuf + s * 128 + 16];
        const bf16x8 B0 = Bf[g_lin & 3][0], B1 = Bf[g_lin & 3][1], B2 = Bf[g_lin & 3][2],
                     B3 = Bf[g_lin & 3][3], B4 = Bf[g_lin & 3][4];
        if (g_lin + 4 < 16) {
#pragma unroll
            for (int t = 0; t < 5; ++t) Bf[g_lin & 3][t] = bb[((g_lin + 4) * 5 + t) * 64];
        }
        bf16x8 xh, xl;
#define CVT(F, I) { const unsigned short h_ = f2bf(F); xh[I] = (short)h_; \
                    xl[I] = (short)f2bf((F) - bf2f(h_)); }
        CVT(a0.x, 0) CVT(a0.y, 1) CVT(a0.z, 2) CVT(a0.w, 3)
        CVT(a1.x, 4) CVT(a1.y, 5) CVT(a1.z, 6) CVT(a1.w, 7)
#undef CVT
        acc0 = __builtin_amdgcn_mfma_f32_16x16x32_bf16(xh, B0, acc0, 0, 0, 0);
        acc1 = __builtin_amdgcn_mfma_f32_16x16x32_bf16(xh, B1, acc1, 0, 0, 0);
        acc2 = __builtin_amdgcn_mfma_f32_16x16x32_bf16(xh, B2, acc2, 0, 0, 0);
        acc3 = __builtin_amdgcn_mfma_f32_16x16x32_bf16(xh, B3, acc3, 0, 0, 0);
        acc4 = __builtin_amdgcn_mfma_f32_16x16x32_bf16(xh, B4, acc4, 0, 0, 0);
        acc4 = __builtin_amdgcn_mfma_f32_16x16x32_bf16(xl, B4, acc4, 0, 0, 0);
    };

    // ---- pipeline: stage 1 chunk ahead; no barriers ----
    stage(0);
#pragma unroll
    for (int i = 0; i < 4; ++i)
#pragma unroll
        for (int t = 0; t < 5; ++t) Bf[i][t] = bb[(i * 5 + t) * 64];
    commit(0);
    stage(1);
#pragma unroll
    for (int s = 0; s < 4; ++s) kstep(s, 0);
    commit(1);
    stage(2);
#pragma unroll
    for (int s = 0; s < 4; ++s) kstep(4 + s, BUFB);
    commit(2);
    stage(3);
#pragma unroll
    for (int s = 0; s < 4; ++s) kstep(8 + s, 0);
    commit(3);
#pragma unroll
    for (int s = 0; s < 4; ++s) kstep(12 + s, BUFB);

    // ---- split-K combine: wave 1 parks partials in ITS OWN (dead) buffer area ----
    if (w == 1) {
        *(f32x4*)&sb[RED + 0 * 1024 + l * 16] = acc0;
        *(f32x4*)&sb[RED + 1 * 1024 + l * 16] = acc1;
        *(f32x4*)&sb[RED + 2 * 1024 + l * 16] = acc2;
        *(f32x4*)&sb[RED + 3 * 1024 + l * 16] = acc3;
        *(f32x4*)&sb[RED + 4 * 1024 + l * 16] = acc4;
    }
    __syncthreads();
    if (w == 1) return;

    acc0 += *(const f32x4*)&sb[RED + 0 * 1024 + l * 16];
    acc1 += *(const f32x4*)&sb[RED + 1 * 1024 + l * 16];
    acc2 += *(const f32x4*)&sb[RED + 2 * 1024 + l * 16];
    acc3 += *(const f32x4*)&sb[RED + 3 * 1024 + l * 16];
    acc4 += *(const f32x4*)&sb[RED + 4 * 1024 + l * 16];

    // ---- epilogue (wave 0 only, intra-wave) ----
    const bf16x8* w2b = (const bf16x8*)w2f + l;
    bf16x8 W2[6];
#pragma unroll
    for (int f = 0; f < 6; ++f) W2[f] = w2b[f * 64];
    const bf16x8* w3b = (const bf16x8*)w3f + l;
    bf16x8 W3[4];
#pragma unroll
    for (int f = 0; f < 4; ++f) W3[f] = w3b[f * 64];

    const float q2c = consts[0], q3c = consts[1], Ccc = consts[2];
    const float bo = b_out[0];
    const float wo0 = w_out[1024 + ar];
    const float wo1 = (ar < 8) ? w_out[1040 + ar] : 0.f;
    float b1p[4], g1p[4], be1p[4], m1p[4], iv1p[4];
#pragma unroll
    for (int t = 0; t < 4; ++t) {
        const int c = t * 16 + ar;
        b1p[t] = b1[c]; g1p[t] = g1[c]; be1p[t] = be1[c]; m1p[t] = m1[c];
        iv1p[t] = rsqrtf(v1[c] + EPS);
    }
    float b2p[3], g2p[3], be2p[3], m2p[3], iv2p[3];
#pragma unroll
    for (int t = 0; t < 3; ++t) {
        const int c = t * 16 + ar;
        b2p[t] = b2[c]; g2p[t] = g2[c]; be2p[t] = be2[c]; m2p[t] = m2[c];
        iv2p[t] = rsqrtf(v2[c] + EPS);
    }
    float b3p[2], g3p[2], be3p[2], m3p[2], iv3p[2];
#pragma unroll
    for (int t = 0; t < 2; ++t) {
        const int c = t == 0 ? ar : (16 + ar < 24 ? 16 + ar : 23);
        b3p[t] = b3[c]; g3p[t] = g3[c]; be3p[t] = be3[c]; m3p[t] = m3[c];
        iv3p[t] = rsqrtf(v3[c] + EPS);
    }

    // cross scalars: fold lo cols (4..7) into hi (0..3), park per-row in LDS
    {
        f32x4 p4 = acc4;
#pragma unroll
        for (int q = 0; q < 4; ++q) p4[q] += __shfl_xor(acc4[q], 4, 64);
        if (ar < 4) {
#pragma unroll
            for (int q = 0; q < 4; ++q)
                *(float*)&sb[LC + ((ag * 4 + q) * 4 + ar) * 4] = p4[q];
        }
    }

    // BN1 + relu, write h1 tile [16 rows][64 cols] f32, row stride 272B
    {
        const f32x4 av[4] = {acc0, acc1, acc2, acc3};
#pragma unroll
        for (int t = 0; t < 4; ++t) {
            const int c = t * 16 + ar;
#pragma unroll
            for (int q = 0; q < 4; ++q) {
                const float y = fmaxf(av[t][q] + b1p[t], 0.f);
                const float h = fmaf(g1p[t] * (y - m1p[t]), iv1p[t], be1p[t]);
                *(float*)&sb[H1 + (ag * 4 + q) * 272 + c * 4] = h;
            }
        }
    }
    // zero-fill h2 cols 48..63 (finite garbage guard for layer-3 A)
    {
        const f32x4 z4 = {0.f, 0.f, 0.f, 0.f};
        *(f32x4*)&sb[H2 + ar * 272 + 192 + ag * 16] = z4;
    }

    // layer 2: h1 -> (tanh,BN) -> h2   via MFMA
    bf16x8 a2[2];
#pragma unroll
    for (int K = 0; K < 2; ++K) {
        const float4 f0 = *(const float4*)&sb[H1 + ar * 272 + (K * 32 + ag * 8) * 4];
        const float4 f1 = *(const float4*)&sb[H1 + ar * 272 + (K * 32 + ag * 8) * 4 + 16];
        const float v[8] = {f0.x, f0.y, f0.z, f0.w, f1.x, f1.y, f1.z, f1.w};
#pragma unroll
        for (int i = 0; i < 8; ++i) a2[K][i] = (short)f2bf(v[i]);
    }
    f32x4 c2t[3] = {{0.f,0.f,0.f,0.f},{0.f,0.f,0.f,0.f},{0.f,0.f,0.f,0.f}};
#pragma unroll
    for (int K = 0; K < 2; ++K) {
        c2t[0] = __builtin_amdgcn_mfma_f32_16x16x32_bf16(a2[K], W2[K * 3 + 0], c2t[0], 0, 0, 0);
        c2t[1] = __builtin_amdgcn_mfma_f32_16x16x32_bf16(a2[K], W2[K * 3 + 1], c2t[1], 0, 0, 0);
        c2t[2] = __builtin_amdgcn_mfma_f32_16x16x32_bf16(a2[K], W2[K * 3 + 2], c2t[2], 0, 0, 0);
    }
#pragma unroll
    for (int t = 0; t < 3; ++t) {
        const int c = t * 16 + ar;
#pragma unroll
        for (int q = 0; q < 4; ++q) {
            const float th = tanh_fast(c2t[t][q] + b2p[t]);
            const float h = fmaf(g2p[t] * (th - m2p[t]), iv2p[t], be2p[t]);
            *(float*)&sb[H2 + (ag * 4 + q) * 272 + c * 4] = h;
        }
    }

    // layer 3: h2 -> (tanh,BN) -> h3   via MFMA (w3 zero-padded handles k/col tails)
    bf16x8 a3[2];
#pragma unroll
    for (int K = 0; K < 2; ++K) {
        const float4 f0 = *(const float4*)&sb[H2 + ar * 272 + (K * 32 + ag * 8) * 4];
        const float4 f1 = *(const float4*)&sb[H2 + ar * 272 + (K * 32 + ag * 8) * 4 + 16];
        const float v[8] = {f0.x, f0.y, f0.z, f0.w, f1.x, f1.y, f1.z, f1.w};
#pragma unroll
        for (int i = 0; i < 8; ++i) a3[K][i] = (short)f2bf(v[i]);
    }
    f32x4 c3t[2] = {{0.f,0.f,0.f,0.f},{0.f,0.f,0.f,0.f}};
#pragma unroll
    for (int K = 0; K < 2; ++K) {
        c3t[0] = __builtin_amdgcn_mfma_f32_16x16x32_bf16(a3[K], W3[K * 2 + 0], c3t[0], 0, 0, 0);
        c3t[1] = __builtin_amdgcn_mfma_f32_16x16x32_bf16(a3[K], W3[K * 2 + 1], c3t[1], 0, 0, 0);
    }
    // tanh+BN3, weighted col-sum (wo1=0 masks cols>=24), 16-lane tree reduce
    float contrib[4];
#pragma unroll
    for (int q = 0; q < 4; ++q) {
        const float t0 = tanh_fast(c3t[0][q] + b3p[0]);
        const float h0 = fmaf(g3p[0] * (t0 - m3p[0]), iv3p[0], be3p[0]);
        const float t1 = tanh_fast(c3t[1][q] + b3p[1]);
        const float h1v = fmaf(g3p[1] * (t1 - m3p[1]), iv3p[1], be3p[1]);
        contrib[q] = h0 * wo0 + h1v * wo1;
    }
#pragma unroll
    for (int m = 1; m < 16; m <<= 1) {
#pragma unroll
        for (int q = 0; q < 4; ++q) contrib[q] += __shfl_xor(contrib[q], m, 64);
    }

    // cross recurrence + sigmoid + store (lane ar==q writes row ag*4+q)
#pragma unroll
    for (int q = 0; q < 4; ++q) {
        const f32x4 pr = *(const f32x4*)&sb[LC + (ag * 4 + q) * 16];
        const float p1 = pr[0], p2 = pr[1], p3 = pr[2], d0 = pr[3];
        const float s1 = p1;
        const float s2 = fmaf(1.f + s1, p2, q2c);
        const float s3 = fmaf(1.f + s1 + s2, p3, q3c);
        const float alpha = 1.f + s1 + s2 + s3;
        const float z = fmaf(alpha, d0, Ccc) + contrib[q] + bo;
        const float o = sigmoid_fast(z);
        if (ar == q) out[gr0 + ag * 4 + q] = o;
    }
}

extern "C" void kernel_launch(void* const* d_in, const int* in_sizes, int n_in,
                              void* d_out, int out_size, void* d_ws, size_t ws_size,
                              hipStream_t stream) {
    const float* x       = (const float*)d_in[0];
    const float* cross_w = (const float*)d_in[1];
    const float* cross_b = (const float*)d_in[2];
    const float* w1      = (const float*)d_in[3];
    const float* b1      = (const float*)d_in[4];
    const float* g1      = (const float*)d_in[5];
    const float* be1     = (const float*)d_in[6];
    const float* m1      = (const float*)d_in[7];
    const float* v1      = (const float*)d_in[8];
    const float* w2      = (const float*)d_in[9];
    const float* b2      = (const float*)d_in[10];
    const float* g2      = (const float*)d_in[11];
    const float* be2     = (const float*)d_in[12];
    const float* m2      = (const float*)d_in[13];
    const float* v2      = (const float*)d_in[14];
    const float* w3      = (const float*)d_in[15];
    const float* b3      = (const float*)d_in[16];
    const float* g3      = (const float*)d_in[17];
    const float* be3     = (const float*)d_in[18];
    const float* m3      = (const float*)d_in[19];
    const float* v3      = (const float*)d_in[20];
    const float* w_out   = (const float*)d_in[21];
    const float* b_out   = (const float*)d_in[22];
    float* out = (float*)d_out;

    unsigned short* ws = (unsigned short*)d_ws;
    const unsigned short* w2f = (const unsigned short*)((char*)d_ws + WB2_OFF);
    const unsigned short* w3f = (const unsigned short*)((char*)d_ws + WB3_OFF);
    const float* consts = (const float*)((char*)d_ws + CST_OFF);

    dcn_prep<<<44, 256, 0, stream>>>(w1, cross_w, cross_b, w_out, w2, w3, ws);
    dcn_main<<<1024, 128, 0, stream>>>(x, ws, w2f, w3f, consts,
                                       b1, g1, be1, m1, v1,
                                       b2, g2, be2, m2, v2,
                                       b3, g3, be3, m3, v3,
                                       w_out, b_out, out);
}

// Round 7
// 26.018 us; speedup vs baseline: 1.4141x; 1.4141x over previous
//
#include <hip/hip_runtime.h>
#include <hip/hip_bf16.h>
#include <math.h>

typedef __attribute__((ext_vector_type(8))) short bf16x8;
typedef __attribute__((ext_vector_type(4))) float f32x4;

constexpr int BD = 1024;
constexpr float EPS = 1e-3f;
// d_ws layout
constexpr int WB_MAIN = 32 * 5 * 64 * 8 * 2;    // 163840  [32 ksteps][5 tiles][64 lanes][8 bf16]
constexpr int WB2_OFF = WB_MAIN;                 // w2 frags: 6*64*8*2 = 6144
constexpr int WB3_OFF = WB2_OFF + 6144;          // w3 frags: 4*64*8*2 = 4096
constexpr int CST_OFF = WB3_OFF + 4096;          // 3 floats

__device__ __forceinline__ float wave_allsum(float v) {
#pragma unroll
    for (int m = 1; m < 64; m <<= 1) v += __shfl_xor(v, m, 64);
    return v;
}
__device__ __forceinline__ unsigned short f2bf(float f) {
    __hip_bfloat16 h = __float2bfloat16(f);   // RNE
    unsigned short u; __builtin_memcpy(&u, &h, 2);
    return u;
}
__device__ __forceinline__ float bf2f(unsigned short u) {
    return __uint_as_float(((unsigned)u) << 16);
}
// 2 floats -> packed bf16x2 (RNE), single HW instruction on gfx950
__device__ __forceinline__ unsigned cvt_pk_bf16(float lo, float hi) {
    unsigned r;
    asm("v_cvt_pk_bf16_f32 %0, %1, %2" : "=v"(r) : "v"(lo), "v"(hi));
    return r;
}
__device__ __forceinline__ float tanh_fast(float x) {
    const float xc = fminf(fmaxf(x, -15.f), 15.f);
    const float e = __expf(2.f * xc);
    return (e - 1.f) * __builtin_amdgcn_rcpf(e + 1.f);
}
__device__ __forceinline__ float sigmoid_fast(float z) {
    return __builtin_amdgcn_rcpf(1.f + __expf(-z));
}

// ---------------- prep: bf16 B-fragments (w1+cross, w2, w3) + cross constants ----------------
__global__ void dcn_prep(const float* __restrict__ w1,
                         const float* __restrict__ cross_w,
                         const float* __restrict__ cross_b,
                         const float* __restrict__ w_out,
                         const float* __restrict__ w2,
                         const float* __restrict__ w3,
                         unsigned short* __restrict__ ws) {
    const int bx = blockIdx.x;
    if (bx == 40) {                       // cross constants
        if (threadIdx.x < 64) {
            const int l = threadIdx.x;
            float q2 = 0.f, q3 = 0.f, Cc = 0.f;
            for (int j = 0; j < 16; ++j) {
                const int k = l * 16 + j;
                const float c0 = cross_b[k], c1 = cross_b[BD + k], c2 = cross_b[2 * BD + k];
                q2 += c0 * cross_w[BD + k];
                q3 += (c0 + c1) * cross_w[2 * BD + k];
                Cc += (c0 + c1 + c2) * w_out[k];
            }
            q2 = wave_allsum(q2); q3 = wave_allsum(q3); Cc = wave_allsum(Cc);
            float* consts = (float*)((char*)ws + CST_OFF);
            if (l == 0) { consts[0] = q2; consts[1] = q3; consts[2] = Cc; }
        }
        return;
    }
    if (bx < 40) {                        // main-GEMM fragments
        const int idx = bx * 256 + threadIdx.x;   // [0, 10240)
        const int g = idx / 320;          // k-step 0..31
        const int rem = idx - g * 320;
        const int t = rem >> 6;           // tile 0..4
        const int l = rem & 63;
        const int c = l & 15;
        const int k0 = g * 32 + (l >> 4) * 8;
        unsigned short o[8] __attribute__((aligned(16)));
#pragma unroll
        for (int j = 0; j < 8; ++j) {
            const int k = k0 + j;
            unsigned short r;
            if (t < 4) {
                r = f2bf(w1[k * 64 + t * 16 + c]);
            } else if (c < 8) {
                const int vsel = c & 3;
                const float v = (vsel < 3) ? cross_w[vsel * BD + k] : w_out[k];
                const unsigned short h = f2bf(v);
                r = (c < 4) ? h : f2bf(v - bf2f(h));
            } else {
                r = 0;
            }
            o[j] = r;
        }
        *(uint4*)(ws + (size_t)idx * 8) = *(const uint4*)o;
        return;
    }
    // bx in 41..43 : tower fragments
    const int slot = (bx - 41) * 256 + threadIdx.x;   // [0, 768)
    if (slot < 384) {                     // w2: f = K*3+T, frag [64][8]
        const int f = slot >> 6, l = slot & 63;
        const int K = f / 3, T = f % 3;
        const int kb = K * 32 + (l >> 4) * 8;
        const int col = T * 16 + (l & 15);
        unsigned short o[8] __attribute__((aligned(16)));
#pragma unroll
        for (int j = 0; j < 8; ++j) o[j] = f2bf(w2[(kb + j) * 48 + col]);
        unsigned short* wb2 = (unsigned short*)((char*)ws + WB2_OFF);
        *(uint4*)(wb2 + (size_t)slot * 8) = *(const uint4*)o;
    } else if (slot < 640) {              // w3: f = K*2+T (zero-padded k>=48, col>=24)
        const int s2 = slot - 384;
        const int f = s2 >> 6, l = s2 & 63;
        const int K = f >> 1, T = f & 1;
        const int kb = K * 32 + (l >> 4) * 8;
        const int col = T * 16 + (l & 15);
        unsigned short o[8] __attribute__((aligned(16)));
#pragma unroll
        for (int j = 0; j < 8; ++j) {
            const int k = kb + j;
            o[j] = (k < 48 && col < 24) ? f2bf(w3[k * 24 + col]) : (unsigned short)0;
        }
        unsigned short* wb3 = (unsigned short*)((char*)ws + WB3_OFF);
        *(uint4*)(wb3 + (size_t)s2 * 8) = *(const uint4*)o;
    }
}

// ---------------- main: 2 waves split K over a 16-row tile; 1 barrier ----------------
__global__ __launch_bounds__(128, 2) void dcn_main(
    const float* __restrict__ x,
    const unsigned short* __restrict__ wbm,
    const unsigned short* __restrict__ w2f,
    const unsigned short* __restrict__ w3f,
    const float* __restrict__ consts,
    const float* __restrict__ b1, const float* __restrict__ g1,
    const float* __restrict__ be1, const float* __restrict__ m1, const float* __restrict__ v1,
    const float* __restrict__ b2, const float* __restrict__ g2,
    const float* __restrict__ be2, const float* __restrict__ m2, const float* __restrict__ v2,
    const float* __restrict__ b3, const float* __restrict__ g3,
    const float* __restrict__ be3, const float* __restrict__ m3, const float* __restrict__ v3,
    const float* __restrict__ w_out, const float* __restrict__ b_out,
    float* __restrict__ out)
{
    // LDS: RED (wave-1 partials, 5 planes x 1KB) | h1 [16x272B] | h2 [16x272B] | lc [16x16B]
    __shared__ char sb[14336] __attribute__((aligned(16)));
    constexpr int RED = 0, H1 = 5120, H2 = 9472, LC = 13824;

    const int tid = threadIdx.x;
    const int l = tid & 63;               // lane
    const int w = tid >> 6;               // wave 0/1 = K half
    const int ar = l & 15;                // fragment row
    const int ag = l >> 4;                // k sub-block
    const int gr0 = blockIdx.x * 16;

    const float* xbase = x + (size_t)(gr0 + ar) * BD + w * 512 + ag * 8;
    const bf16x8* bb = (const bf16x8*)wbm + (size_t)(w * 16 * 5) * 64 + l;

    // ---- main K loop (16 steps/wave): A 8-deep, B 4-deep prefetch ----
    float4 A0[8], A1[8];
#pragma unroll
    for (int s = 0; s < 8; ++s) {
        A0[s] = *(const float4*)(xbase + s * 32);
        A1[s] = *(const float4*)(xbase + s * 32 + 4);
    }
    bf16x8 Bf[4][5];
#pragma unroll
    for (int s = 0; s < 4; ++s)
#pragma unroll
        for (int t = 0; t < 5; ++t) Bf[s][t] = bb[(s * 5 + t) * 64];

    f32x4 acc0 = {0.f,0.f,0.f,0.f}, acc1 = acc0, acc2 = acc0, acc3 = acc0, acc4 = acc0;

#pragma unroll
    for (int s = 0; s < 16; ++s) {
        const float4 va0 = A0[s & 7];
        const float4 va1 = A1[s & 7];
        if (s < 8) {   // reload slot for step s+8
            A0[s & 7] = *(const float4*)(xbase + (s + 8) * 32);
            A1[s & 7] = *(const float4*)(xbase + (s + 8) * 32 + 4);
        }
        const bf16x8 B0 = Bf[s & 3][0], B1 = Bf[s & 3][1], B2 = Bf[s & 3][2],
                     B3 = Bf[s & 3][3], B4 = Bf[s & 3][4];
        if (s + 4 < 16) {
#pragma unroll
            for (int t = 0; t < 5; ++t) Bf[s & 3][t] = bb[((s + 4) * 5 + t) * 64];
        }
        // ---- split-precision conversion via v_cvt_pk_bf16_f32 ----
        union { unsigned u[4]; bf16x8 v; } XH, XL;
        XH.u[0] = cvt_pk_bf16(va0.x, va0.y);
        XH.u[1] = cvt_pk_bf16(va0.z, va0.w);
        XH.u[2] = cvt_pk_bf16(va1.x, va1.y);
        XH.u[3] = cvt_pk_bf16(va1.z, va1.w);
        // exact residuals: x - bf2f(round(x))  (Sterbenz: exact in f32)
        const float l0 = va0.x - __uint_as_float(XH.u[0] << 16);
        const float l1 = va0.y - __uint_as_float(XH.u[0] & 0xFFFF0000u);
        const float l2 = va0.z - __uint_as_float(XH.u[1] << 16);
        const float l3 = va0.w - __uint_as_float(XH.u[1] & 0xFFFF0000u);
        const float l4 = va1.x - __uint_as_float(XH.u[2] << 16);
        const float l5 = va1.y - __uint_as_float(XH.u[2] & 0xFFFF0000u);
        const float l6 = va1.z - __uint_as_float(XH.u[3] << 16);
        const float l7 = va1.w - __uint_as_float(XH.u[3] & 0xFFFF0000u);
        XL.u[0] = cvt_pk_bf16(l0, l1);
        XL.u[1] = cvt_pk_bf16(l2, l3);
        XL.u[2] = cvt_pk_bf16(l4, l5);
        XL.u[3] = cvt_pk_bf16(l6, l7);

        acc0 = __builtin_amdgcn_mfma_f32_16x16x32_bf16(XH.v, B0, acc0, 0, 0, 0);
        acc1 = __builtin_amdgcn_mfma_f32_16x16x32_bf16(XH.v, B1, acc1, 0, 0, 0);
        acc2 = __builtin_amdgcn_mfma_f32_16x16x32_bf16(XH.v, B2, acc2, 0, 0, 0);
        acc3 = __builtin_amdgcn_mfma_f32_16x16x32_bf16(XH.v, B3, acc3, 0, 0, 0);
        acc4 = __builtin_amdgcn_mfma_f32_16x16x32_bf16(XH.v, B4, acc4, 0, 0, 0);
        acc4 = __builtin_amdgcn_mfma_f32_16x16x32_bf16(XL.v, B4, acc4, 0, 0, 0);
    }

    // ---- split-K combine: wave 1 parks partials, wave 0 sums and finishes ----
    if (w == 1) {
        *(f32x4*)&sb[RED + 0 * 1024 + l * 16] = acc0;
        *(f32x4*)&sb[RED + 1 * 1024 + l * 16] = acc1;
        *(f32x4*)&sb[RED + 2 * 1024 + l * 16] = acc2;
        *(f32x4*)&sb[RED + 3 * 1024 + l * 16] = acc3;
        *(f32x4*)&sb[RED + 4 * 1024 + l * 16] = acc4;
    }
    __syncthreads();
    if (w == 1) return;

    acc0 += *(const f32x4*)&sb[RED + 0 * 1024 + l * 16];
    acc1 += *(const f32x4*)&sb[RED + 1 * 1024 + l * 16];
    acc2 += *(const f32x4*)&sb[RED + 2 * 1024 + l * 16];
    acc3 += *(const f32x4*)&sb[RED + 3 * 1024 + l * 16];
    acc4 += *(const f32x4*)&sb[RED + 4 * 1024 + l * 16];

    // ---- epilogue (wave 0 only, intra-wave) ----
    const bf16x8* w2b = (const bf16x8*)w2f + l;
    bf16x8 W2[6];
#pragma unroll
    for (int f = 0; f < 6; ++f) W2[f] = w2b[f * 64];
    const bf16x8* w3b = (const bf16x8*)w3f + l;
    bf16x8 W3[4];
#pragma unroll
    for (int f = 0; f < 4; ++f) W3[f] = w3b[f * 64];

    const float q2c = consts[0], q3c = consts[1], Ccc = consts[2];
    const float bo = b_out[0];
    const float wo0 = w_out[1024 + ar];
    const float wo1 = (ar < 8) ? w_out[1040 + ar] : 0.f;
    float b1p[4], g1p[4], be1p[4], m1p[4], iv1p[4];
#pragma unroll
    for (int t = 0; t < 4; ++t) {
        const int c = t * 16 + ar;
        b1p[t] = b1[c]; g1p[t] = g1[c]; be1p[t] = be1[c]; m1p[t] = m1[c];
        iv1p[t] = rsqrtf(v1[c] + EPS);
    }
    float b2p[3], g2p[3], be2p[3], m2p[3], iv2p[3];
#pragma unroll
    for (int t = 0; t < 3; ++t) {
        const int c = t * 16 + ar;
        b2p[t] = b2[c]; g2p[t] = g2[c]; be2p[t] = be2[c]; m2p[t] = m2[c];
        iv2p[t] = rsqrtf(v2[c] + EPS);
    }
    float b3p[2], g3p[2], be3p[2], m3p[2], iv3p[2];
#pragma unroll
    for (int t = 0; t < 2; ++t) {
        const int c = t == 0 ? ar : (16 + ar < 24 ? 16 + ar : 23);
        b3p[t] = b3[c]; g3p[t] = g3[c]; be3p[t] = be3[c]; m3p[t] = m3[c];
        iv3p[t] = rsqrtf(v3[c] + EPS);
    }

    // cross scalars: fold lo cols (4..7) into hi (0..3), park per-row in LDS
    {
        f32x4 p4 = acc4;
#pragma unroll
        for (int q = 0; q < 4; ++q) p4[q] += __shfl_xor(acc4[q], 4, 64);
        if (ar < 4) {
#pragma unroll
            for (int q = 0; q < 4; ++q)
                *(float*)&sb[LC + ((ag * 4 + q) * 4 + ar) * 4] = p4[q];
        }
    }

    // BN1 + relu, write h1 tile [16 rows][64 cols] f32, row stride 272B
    {
        const f32x4 av[4] = {acc0, acc1, acc2, acc3};
#pragma unroll
        for (int t = 0; t < 4; ++t) {
            const int c = t * 16 + ar;
#pragma unroll
            for (int q = 0; q < 4; ++q) {
                const float y = fmaxf(av[t][q] + b1p[t], 0.f);
                const float h = fmaf(g1p[t] * (y - m1p[t]), iv1p[t], be1p[t]);
                *(float*)&sb[H1 + (ag * 4 + q) * 272 + c * 4] = h;
            }
        }
    }
    // zero-fill h2 cols 48..63 (finite garbage guard for layer-3 A)
    {
        const f32x4 z4 = {0.f, 0.f, 0.f, 0.f};
        *(f32x4*)&sb[H2 + ar * 272 + 192 + ag * 16] = z4;
    }

    // layer 2: h1 -> (tanh,BN) -> h2   via MFMA
    bf16x8 a2[2];
#pragma unroll
    for (int K = 0; K < 2; ++K) {
        const float4 f0 = *(const float4*)&sb[H1 + ar * 272 + (K * 32 + ag * 8) * 4];
        const float4 f1 = *(const float4*)&sb[H1 + ar * 272 + (K * 32 + ag * 8) * 4 + 16];
        union { unsigned u[4]; bf16x8 v; } P;
        P.u[0] = cvt_pk_bf16(f0.x, f0.y);
        P.u[1] = cvt_pk_bf16(f0.z, f0.w);
        P.u[2] = cvt_pk_bf16(f1.x, f1.y);
        P.u[3] = cvt_pk_bf16(f1.z, f1.w);
        a2[K] = P.v;
    }
    f32x4 c2t[3] = {{0.f,0.f,0.f,0.f},{0.f,0.f,0.f,0.f},{0.f,0.f,0.f,0.f}};
#pragma unroll
    for (int K = 0; K < 2; ++K) {
        c2t[0] = __builtin_amdgcn_mfma_f32_16x16x32_bf16(a2[K], W2[K * 3 + 0], c2t[0], 0, 0, 0);
        c2t[1] = __builtin_amdgcn_mfma_f32_16x16x32_bf16(a2[K], W2[K * 3 + 1], c2t[1], 0, 0, 0);
        c2t[2] = __builtin_amdgcn_mfma_f32_16x16x32_bf16(a2[K], W2[K * 3 + 2], c2t[2], 0, 0, 0);
    }
#pragma unroll
    for (int t = 0; t < 3; ++t) {
        const int c = t * 16 + ar;
#pragma unroll
        for (int q = 0; q < 4; ++q) {
            const float th = tanh_fast(c2t[t][q] + b2p[t]);
            const float h = fmaf(g2p[t] * (th - m2p[t]), iv2p[t], be2p[t]);
            *(float*)&sb[H2 + (ag * 4 + q) * 272 + c * 4] = h;
        }
    }

    // layer 3: h2 -> (tanh,BN) -> h3   via MFMA (w3 zero-padded handles k/col tails)
    bf16x8 a3[2];
#pragma unroll
    for (int K = 0; K < 2; ++K) {
        const float4 f0 = *(const float4*)&sb[H2 + ar * 272 + (K * 32 + ag * 8) * 4];
        const float4 f1 = *(const float4*)&sb[H2 + ar * 272 + (K * 32 + ag * 8) * 4 + 16];
        union { unsigned u[4]; bf16x8 v; } P;
        P.u[0] = cvt_pk_bf16(f0.x, f0.y);
        P.u[1] = cvt_pk_bf16(f0.z, f0.w);
        P.u[2] = cvt_pk_bf16(f1.x, f1.y);
        P.u[3] = cvt_pk_bf16(f1.z, f1.w);
        a3[K] = P.v;
    }
    f32x4 c3t[2] = {{0.f,0.f,0.f,0.f},{0.f,0.f,0.f,0.f}};
#pragma unroll
    for (int K = 0; K < 2; ++K) {
        c3t[0] = __builtin_amdgcn_mfma_f32_16x16x32_bf16(a3[K], W3[K * 2 + 0], c3t[0], 0, 0, 0);
        c3t[1] = __builtin_amdgcn_mfma_f32_16x16x32_bf16(a3[K], W3[K * 2 + 1], c3t[1], 0, 0, 0);
    }
    // tanh+BN3, weighted col-sum (wo1=0 masks cols>=24), 16-lane tree reduce
    float contrib[4];
#pragma unroll
    for (int q = 0; q < 4; ++q) {
        const float t0 = tanh_fast(c3t[0][q] + b3p[0]);
        const float h0 = fmaf(g3p[0] * (t0 - m3p[0]), iv3p[0], be3p[0]);
        const float t1 = tanh_fast(c3t[1][q] + b3p[1]);
        const float h1v = fmaf(g3p[1] * (t1 - m3p[1]), iv3p[1], be3p[1]);
        contrib[q] = h0 * wo0 + h1v * wo1;
    }
#pragma unroll
    for (int m = 1; m < 16; m <<= 1) {
#pragma unroll
        for (int q = 0; q < 4; ++q) contrib[q] += __shfl_xor(contrib[q], m, 64);
    }

    // cross recurrence + sigmoid + store (lane ar==q writes row ag*4+q)
#pragma unroll
    for (int q = 0; q < 4; ++q) {
        const f32x4 pr = *(const f32x4*)&sb[LC + (ag * 4 + q) * 16];
        const float p1 = pr[0], p2 = pr[1], p3 = pr[2], d0 = pr[3];
        const float s1 = p1;
        const float s2 = fmaf(1.f + s1, p2, q2c);
        const float s3 = fmaf(1.f + s1 + s2, p3, q3c);
        const float alpha = 1.f + s1 + s2 + s3;
        const float z = fmaf(alpha, d0, Ccc) + contrib[q] + bo;
        const float o = sigmoid_fast(z);
        if (ar == q) out[gr0 + ag * 4 + q] = o;
    }
}

extern "C" void kernel_launch(void* const* d_in, const int* in_sizes, int n_in,
                              void* d_out, int out_size, void* d_ws, size_t ws_size,
                              hipStream_t stream) {
    const float* x       = (const float*)d_in[0];
    const float* cross_w = (const float*)d_in[1];
    const float* cross_b = (const float*)d_in[2];
    const float* w1      = (const float*)d_in[3];
    const float* b1      = (const float*)d_in[4];
    const float* g1      = (const float*)d_in[5];
    const float* be1     = (const float*)d_in[6];
    const float* m1      = (const float*)d_in[7];
    const float* v1      = (const float*)d_in[8];
    const float* w2      = (const float*)d_in[9];
    const float* b2      = (const float*)d_in[10];
    const float* g2      = (const float*)d_in[11];
    const float* be2     = (const float*)d_in[12];
    const float* m2      = (const float*)d_in[13];
    const float* v2      = (const float*)d_in[14];
    const float* w3      = (const float*)d_in[15];
    const float* b3      = (const float*)d_in[16];
    const float* g3      = (const float*)d_in[17];
    const float* be3     = (const float*)d_in[18];
    const float* m3      = (const float*)d_in[19];
    const float* v3      = (const float*)d_in[20];
    const float* w_out   = (const float*)d_in[21];
    const float* b_out   = (const float*)d_in[22];
    float* out = (float*)d_out;

    unsigned short* ws = (unsigned short*)d_ws;
    const unsigned short* w2f = (const unsigned short*)((char*)d_ws + WB2_OFF);
    const unsigned short* w3f = (const unsigned short*)((char*)d_ws + WB3_OFF);
    const float* consts = (const float*)((char*)d_ws + CST_OFF);

    dcn_prep<<<44, 256, 0, stream>>>(w1, cross_w, cross_b, w_out, w2, w3, ws);
    dcn_main<<<1024, 128, 0, stream>>>(x, ws, w2f, w3f, consts,
                                       b1, g1, be1, m1, v1,
                                       b2, g2, be2, m2, v2,
                                       b3, g3, be3, m3, v3,
                                       w_out, b_out, out);
}